// Round 16
// baseline (167.292 us; speedup 1.0000x reference)
//
#include <hip/hip_runtime.h>
#include <cstdint>

using u16 = unsigned short;
using u32 = unsigned int;
typedef __attribute__((ext_vector_type(8))) short bf16x8;
typedef __attribute__((ext_vector_type(8))) u16 u16x8;
typedef __attribute__((ext_vector_type(16))) float f32x16;
typedef __attribute__((ext_vector_type(2))) u32 u32x2;
typedef __attribute__((ext_vector_type(4))) u32 u32x4;

#define DEV static __device__ __forceinline__

DEV u16 bf16_rne(float x) {
  u32 u = __float_as_uint(x);
  u32 r = (u + 0x7FFFu + ((u >> 16) & 1u)) >> 16;
  return (u16)r;
}
DEV float bf16f(u16 h) { return __uint_as_float(((u32)h) << 16); }

DEV u32 cvt_pk_bf16(float lo, float hi) {
  u32 d;
  asm("v_cvt_pk_bf16_f32 %0, %1, %2" : "=v"(d) : "v"(lo), "v"(hi));
  return d;
}

// tanh/sigmoid via v_rcp_f32 (1 ulp) instead of IEEE divide (~10-op chain).
DEV float fast_tanh(float x) {
  float e = __expf(2.0f * x);
  return fmaf(-2.0f, __builtin_amdgcn_rcpf(e + 1.0f), 1.0f);
}
DEV float sigmoidf_(float x) {
  return __builtin_amdgcn_rcpf(1.0f + __expf(-x));
}

// ---------------------------------------------------------------------------
// prep_w: bid<32: WfG = W_seq^T in A-fragment order (unit (pt8*16+kt)*512
// elems: p = pt8*32+(lane&31), d = kt*16+(lane>>5)*8+e).
// bid>=32: GRU weight transposes (lanes = g, coalesced stores).
// ---------------------------------------------------------------------------
__global__ __launch_bounds__(256) void prep_w(const float* __restrict__ Wseq,
                                              const float* __restrict__ Wih,
                                              const float* __restrict__ Whh,
                                              u16* __restrict__ WfG,
                                              float* __restrict__ WT,
                                              float* __restrict__ UT) {
  const int bid = blockIdx.x, t = threadIdx.x;
  if (bid < 32) {
    const int unit = bid * 4 + (t >> 6);
    const int lane = t & 63, l31 = lane & 31, koct = lane >> 5;
    const int pt8 = unit >> 4, kt = unit & 15;
    u16x8 o;
#pragma unroll
    for (int e = 0; e < 8; ++e)
      o[e] = bf16_rne(
          Wseq[(long)(kt * 16 + koct * 8 + e) * 256 + pt8 * 32 + l31]);
    *(u16x8*)(WfG + (long)unit * 512 + lane * 8) = o;
  } else {
    const int gid = bid - 32;  // 0..23
    const float* src = (gid >= 12) ? Whh : Wih;
    float* dst = (gid >= 12) ? UT : WT;
    const int g = (gid % 12) * 64 + (t & 63);
    const int dq = t >> 6;
#pragma unroll 4
    for (int d = dq * 64; d < dq * 64 + 64; ++d)
      dst[(long)d * 768 + g] = src[(long)g * 256 + d];
  }
}

// ---------------------------------------------------------------------------
// hw_q: hw[b][q*64..] = (h[b] @ W_h)[q*64..]; grid (4,B).
// ---------------------------------------------------------------------------
__global__ __launch_bounds__(256) void hw_q(const float* __restrict__ h,
                                            const float* __restrict__ Wh,
                                            float* __restrict__ hw) {
  const int q = blockIdx.x, b = blockIdx.y, t = threadIdx.x;
  __shared__ float sh[256];
  __shared__ float sP[4][64];
  sh[t] = h[b * 256 + t];
  __syncthreads();
  const int j4 = t & 63, dg = t >> 6;
  const int j = q * 64 + j4;
  float g = 0.f;
#pragma unroll 4
  for (int k = dg * 64; k < dg * 64 + 64; ++k)
    g = fmaf(sh[k], Wh[(long)k * 256 + j], g);
  sP[dg][j4] = g;
  __syncthreads();
  if (t < 64)
    hw[b * 256 + q * 64 + t] = (sP[0][t] + sP[1][t]) + (sP[2][t] + sP[3][t]);
}

// ---------------------------------------------------------------------------
// Shared epilogue (128-row chunks): scores via 4-way-split accumulators,
// max-free exp, chunk esum, vec partials (LDS tile or global seqF frags).
// ---------------------------------------------------------------------------
struct EpiSmem {
  float sQ[128][5];
  float se[128];
  float shw[256];
  float svv[256];
  float sredE[2];
};

template <bool FROMLDS>
DEV void epilogue(EpiSmem& sm, const f32x16& a00, const f32x16& a01,
                  const f32x16& a10, const f32x16& a11, const u16* bs,
                  const char* sRb, const float* __restrict__ mask,
                  float* __restrict__ wbuf, float* __restrict__ esum,
                  float* __restrict__ part, long nbase, int esumIdx,
                  long partBase, int t, int lane, int w, int l31, int koct,
                  int pg, int ng) {
  float s0a = 0.f, s0b = 0.f, s0c = 0.f, s0d = 0.f;
  float s1a = 0.f, s1b = 0.f, s1c = 0.f, s1d = 0.f;
#pragma unroll
  for (int r = 0; r < 16; r += 4) {
    const int c0 = (r & 3) + 8 * (r >> 2) + 4 * koct;
    const int c1 = ((r + 1) & 3) + 8 * ((r + 1) >> 2) + 4 * koct;
    const int c2 = ((r + 2) & 3) + 8 * ((r + 2) >> 2) + 4 * koct;
    const int c3 = ((r + 3) & 3) + 8 * ((r + 3) >> 2) + 4 * koct;
    const int p0 = pg * 64 + c0, p1 = pg * 64 + c1, p2 = pg * 64 + c2,
              p3 = pg * 64 + c3;
    s0a = fmaf(sm.svv[p0], fast_tanh(a00[r] + sm.shw[p0]), s0a);
    s0b = fmaf(sm.svv[p1], fast_tanh(a00[r + 1] + sm.shw[p1]), s0b);
    s0c = fmaf(sm.svv[p2], fast_tanh(a00[r + 2] + sm.shw[p2]), s0c);
    s0d = fmaf(sm.svv[p3], fast_tanh(a00[r + 3] + sm.shw[p3]), s0d);
    s1a = fmaf(sm.svv[p0], fast_tanh(a01[r] + sm.shw[p0]), s1a);
    s1b = fmaf(sm.svv[p1], fast_tanh(a01[r + 1] + sm.shw[p1]), s1b);
    s1c = fmaf(sm.svv[p2], fast_tanh(a01[r + 2] + sm.shw[p2]), s1c);
    s1d = fmaf(sm.svv[p3], fast_tanh(a01[r + 3] + sm.shw[p3]), s1d);
  }
#pragma unroll
  for (int r = 0; r < 16; r += 4) {
    const int c0 = (r & 3) + 8 * (r >> 2) + 4 * koct;
    const int c1 = ((r + 1) & 3) + 8 * ((r + 1) >> 2) + 4 * koct;
    const int c2 = ((r + 2) & 3) + 8 * ((r + 2) >> 2) + 4 * koct;
    const int c3 = ((r + 3) & 3) + 8 * ((r + 3) >> 2) + 4 * koct;
    const int p0 = pg * 64 + 32 + c0, p1 = pg * 64 + 32 + c1,
              p2 = pg * 64 + 32 + c2, p3 = pg * 64 + 32 + c3;
    s0a = fmaf(sm.svv[p0], fast_tanh(a10[r] + sm.shw[p0]), s0a);
    s0b = fmaf(sm.svv[p1], fast_tanh(a10[r + 1] + sm.shw[p1]), s0b);
    s0c = fmaf(sm.svv[p2], fast_tanh(a10[r + 2] + sm.shw[p2]), s0c);
    s0d = fmaf(sm.svv[p3], fast_tanh(a10[r + 3] + sm.shw[p3]), s0d);
    s1a = fmaf(sm.svv[p0], fast_tanh(a11[r] + sm.shw[p0]), s1a);
    s1b = fmaf(sm.svv[p1], fast_tanh(a11[r + 1] + sm.shw[p1]), s1b);
    s1c = fmaf(sm.svv[p2], fast_tanh(a11[r + 2] + sm.shw[p2]), s1c);
    s1d = fmaf(sm.svv[p3], fast_tanh(a11[r + 3] + sm.shw[p3]), s1d);
  }
  float sc0 = (s0a + s0b) + (s0c + s0d);
  float sc1 = (s1a + s1b) + (s1c + s1d);
  sc0 += __shfl_xor(sc0, 32, 64);
  sc1 += __shfl_xor(sc1, 32, 64);
  if (koct == 0) {
    sm.sQ[ng * 64 + l31][pg] = sc0;
    sm.sQ[ng * 64 + 32 + l31][pg] = sc1;
  }
  __syncthreads();
  if (t < 128) {
    float s = (sm.sQ[t][0] + sm.sQ[t][1]) + (sm.sQ[t][2] + sm.sQ[t][3]);
    const long n = nbase + t;
    float e = (mask[n] > 0.f) ? __expf(s) : 0.f;
    sm.se[t] = e;
    wbuf[n] = e;
    float s4 = e;
#pragma unroll
    for (int off = 1; off < 64; off <<= 1) s4 += __shfl_xor(s4, off, 64);
    if ((t & 63) == 0) sm.sredE[t >> 6] = s4;
  }
  __syncthreads();
  if (t == 0) esum[esumIdx] = sm.sredE[0] + sm.sredE[1];

  // vec partials: wave w covers kt = w and w+8
#pragma unroll
  for (int kk = 0; kk < 2; ++kk) {
    const int kt = w + kk * 8;
    float vd0 = 0, vd1 = 0, vd2 = 0, vd3 = 0, vd4 = 0, vd5 = 0, vd6 = 0,
          vd7 = 0;
#pragma unroll
    for (int t8 = 0; t8 < 4; ++t8) {
      u16x8 q;
      if constexpr (FROMLDS) {
        const int row = t8 * 32 + l31;
        const int colb = (kt * 16 + koct * 8) * 2;
        q = *(const u16x8*)(sRb + row * 512 + (colb ^ ((row & 31) << 4)));
      } else {
        q = *(const u16x8*)(bs + ((long)(t8 * 16 + kt) * 64 + lane) * 8);
      }
      const float wv = sm.se[t8 * 32 + l31];
      vd0 = fmaf(wv, bf16f((u16)q[0]), vd0);
      vd1 = fmaf(wv, bf16f((u16)q[1]), vd1);
      vd2 = fmaf(wv, bf16f((u16)q[2]), vd2);
      vd3 = fmaf(wv, bf16f((u16)q[3]), vd3);
      vd4 = fmaf(wv, bf16f((u16)q[4]), vd4);
      vd5 = fmaf(wv, bf16f((u16)q[5]), vd5);
      vd6 = fmaf(wv, bf16f((u16)q[6]), vd6);
      vd7 = fmaf(wv, bf16f((u16)q[7]), vd7);
    }
#pragma unroll
    for (int off = 1; off < 32; off <<= 1) {
      vd0 += __shfl_xor(vd0, off, 64);
      vd1 += __shfl_xor(vd1, off, 64);
      vd2 += __shfl_xor(vd2, off, 64);
      vd3 += __shfl_xor(vd3, off, 64);
      vd4 += __shfl_xor(vd4, off, 64);
      vd5 += __shfl_xor(vd5, off, 64);
      vd6 += __shfl_xor(vd6, off, 64);
      vd7 += __shfl_xor(vd7, off, 64);
    }
    if (l31 == 0) {
      float4 o0 = {vd0, vd1, vd2, vd3};
      float4 o1 = {vd4, vd5, vd6, vd7};
      float* pp = part + partBase * 256 + kt * 16 + koct * 8;
      *(float4*)pp = o0;
      *(float4*)(pp + 4) = o1;
    }
  }
}

// ---------------------------------------------------------------------------
// step0k: chunk PAIR per block (512 blocks = exactly 2/CU, single round).
// Pipeline: fill(c0); bar; writeout(c0)+gemm(c0); bar; fill(c1) issued, then
// epilogue(c0) via global seqF (sR free) hides fill(c1) latency; epi's
// internal barriers double as the fill-complete sync; writeout(c1)+gemm(c1);
// bar; epilogue(c1) from LDS.
// ---------------------------------------------------------------------------
__global__ __launch_bounds__(512, 2) void step0k(
    const float* __restrict__ seq, u16* __restrict__ seqF,
    const u16* __restrict__ WfG, const float* __restrict__ hwbuf,
    const float* __restrict__ vatt, const float* __restrict__ mask,
    float* __restrict__ wbuf, float* __restrict__ esum,
    float* __restrict__ part, int N, int NCH2, int B) {
  __shared__ __align__(16) u16 sR[32768];  // 64 KB tile
  __shared__ EpiSmem sm;

  const int t = threadIdx.x, lane = t & 63, w = t >> 6;
  const int l31 = lane & 31, koct = lane >> 5;
  const int pg = w >> 1, ng = w & 1;
  const int b = blockIdx.y;
  const int c0 = blockIdx.x * 2, c1 = c0 + 1;
  char* sRb = (char*)sR;

  auto fill = [&](int ch) {  // dense: each wave reads one 1 KB row per iter
    const float* src = seq + ((long)b * N + ch * 128) * 256;
#pragma unroll
    for (int i = 0; i < 16; ++i) {
      const int idx = i * 2048 + t * 4;
      float4 x = *(const float4*)(src + idx);
      u32x2 o;
      o[0] = cvt_pk_bf16(x.x, x.y);
      o[1] = cvt_pk_bf16(x.z, x.w);
      const int row = idx >> 8, colb = (idx & 255) * 2;
      *(u32x2*)(sRb + row * 512 + (colb ^ ((row & 31) << 4))) = o;
    }
  };
  auto writeout = [&](int ch) {  // sR -> fragment-order seqF
    u16* dst = seqF + ((long)(b * NCH2 + ch) << 15);
#pragma unroll
    for (int i = 0; i < 8; ++i) {
      const int uidx = i * 512 + t;
      const int ln = uidx & 63, unit = uidx >> 6;
      const int kt = unit & 15, t8 = unit >> 4;
      const int row = t8 * 32 + (ln & 31);
      const int colb = (kt * 16 + (ln >> 5) * 8) * 2;
      u16x8 v = *(const u16x8*)(sRb + row * 512 + (colb ^ ((row & 31) << 4)));
      *(u16x8*)(dst + (long)uidx * 8) = v;
    }
  };
  const u16* wa0 = WfG + (long)(pg * 32) * 512 + lane * 8;
  const u16* wa1 = wa0 + 8192;
  auto gemm = [&](f32x16& a00, f32x16& a01, f32x16& a10, f32x16& a11) {
    const int row0 = ng * 64 + l31, row1 = row0 + 32;
    const char* p0 = sRb + row0 * 512;
    const char* p1 = sRb + row1 * 512;
    const int sw0 = (row0 & 31) << 4, sw1 = (row1 & 31) << 4;
    const int cb = koct * 16;
#pragma unroll 4
    for (int kt = 0; kt < 16; ++kt) {
      bf16x8 af0 = *(const bf16x8*)(wa0 + kt * 512);
      bf16x8 af1 = *(const bf16x8*)(wa1 + kt * 512);
      bf16x8 bf0 = *(const bf16x8*)(p0 + ((kt * 32 + cb) ^ sw0));
      bf16x8 bf1 = *(const bf16x8*)(p1 + ((kt * 32 + cb) ^ sw1));
      a00 = __builtin_amdgcn_mfma_f32_32x32x16_bf16(af0, bf0, a00, 0, 0, 0);
      a01 = __builtin_amdgcn_mfma_f32_32x32x16_bf16(af0, bf1, a01, 0, 0, 0);
      a10 = __builtin_amdgcn_mfma_f32_32x32x16_bf16(af1, bf0, a10, 0, 0, 0);
      a11 = __builtin_amdgcn_mfma_f32_32x32x16_bf16(af1, bf1, a11, 0, 0, 0);
    }
  };

  // ===== chunk 0 =====
  fill(c0);
  if (t < 256) {
    sm.shw[t] = hwbuf[b * 256 + t];
    sm.svv[t] = vatt[t];
  }
  __syncthreads();  // tile(c0) + shw/svv ready
  writeout(c0);
  f32x16 a00 = (f32x16)0.f, a01 = (f32x16)0.f, a10 = (f32x16)0.f,
         a11 = (f32x16)0.f;
  gemm(a00, a01, a10, a11);
  __syncthreads();  // all GEMM reads of sR(c0) done; vmcnt drained (writeout)

  // ===== overlap: fill(c1) issued, epilogue(c0) computes on top =====
  fill(c1);
  epilogue<false>(sm, a00, a01, a10, a11,
                  seqF + ((long)(b * NCH2 + c0) << 15), nullptr, mask, wbuf,
                  esum, part, (long)b * N + c0 * 128, b * NCH2 + c0,
                  (long)c0 * B + b, t, lane, w, l31, koct, pg, ng);
  // epi's internal barriers guarantee fill(c1) LDS stores are visible.

  // ===== chunk 1 =====
  writeout(c1);
  f32x16 b00 = (f32x16)0.f, b01 = (f32x16)0.f, b10 = (f32x16)0.f,
         b11 = (f32x16)0.f;
  gemm(b00, b01, b10, b11);
  __syncthreads();
  epilogue<true>(sm, b00, b01, b10, b11, nullptr, sRb, mask, wbuf, esum, part,
                 (long)b * N + c1 * 128, b * NCH2 + c1, (long)c1 * B + b, t,
                 lane, w, l31, koct, pg, ng);
}

// ---------------------------------------------------------------------------
// step1k: barrier-free streaming GEMM. B-frags ring-prefetched from global
// seqF (MFMA order, 64x16B contiguous); W-frags streamed from L2.
// ---------------------------------------------------------------------------
__global__ __launch_bounds__(512, 4) void step1k(
    const u16* __restrict__ seqF, const u16* __restrict__ WfG,
    const float* __restrict__ hwbuf, const float* __restrict__ vatt,
    const float* __restrict__ mask, float* __restrict__ wbuf,
    float* __restrict__ esum, float* __restrict__ part, int N, int NCH2,
    int B) {
  __shared__ EpiSmem sm;
  const int t = threadIdx.x, lane = t & 63, w = t >> 6;
  const int l31 = lane & 31, koct = lane >> 5;
  const int pg = w >> 1, ng = w & 1;
  const int b = blockIdx.y, ch = blockIdx.x;
  const long chbase = (long)(b * NCH2 + ch) << 15;

  if (t < 256) {
    sm.shw[t] = hwbuf[b * 256 + t];
    sm.svv[t] = vatt[t];
  }

  const u16* bs0 = seqF + chbase + ng * 16384 + lane * 8;
  const u16* bs1 = bs0 + 8192;
  const u16* wa0 = WfG + (long)(pg * 32) * 512 + lane * 8;
  const u16* wa1 = wa0 + 8192;

  f32x16 a00 = (f32x16)0.f, a01 = (f32x16)0.f, a10 = (f32x16)0.f,
         a11 = (f32x16)0.f;

  u16x8 A0c, A1c, B0c, B1c, A0n, A1n, B0n, B1n;
  A0c = *(const u16x8*)(wa0);
  A1c = *(const u16x8*)(wa1);
  B0c = *(const u16x8*)(bs0);
  B1c = *(const u16x8*)(bs1);

#define MFMA4(A0, A1, B0, B1)                                                  \
  {                                                                            \
    bf16x8 af0 = *(bf16x8*)&A0, af1 = *(bf16x8*)&A1;                           \
    bf16x8 bf0 = *(bf16x8*)&B0, bf1 = *(bf16x8*)&B1;                           \
    a00 = __builtin_amdgcn_mfma_f32_32x32x16_bf16(af0, bf0, a00, 0, 0, 0);     \
    a01 = __builtin_amdgcn_mfma_f32_32x32x16_bf16(af0, bf1, a01, 0, 0, 0);     \
    a10 = __builtin_amdgcn_mfma_f32_32x32x16_bf16(af1, bf0, a10, 0, 0, 0);     \
    a11 = __builtin_amdgcn_mfma_f32_32x32x16_bf16(af1, bf1, a11, 0, 0, 0);     \
  }

#pragma unroll
  for (int kt2 = 0; kt2 < 8; ++kt2) {
    const int kn = kt2 * 2 + 1;
    A0n = *(const u16x8*)(wa0 + kn * 512);
    A1n = *(const u16x8*)(wa1 + kn * 512);
    B0n = *(const u16x8*)(bs0 + kn * 512);
    B1n = *(const u16x8*)(bs1 + kn * 512);
    MFMA4(A0c, A1c, B0c, B1c);
    if (kt2 < 7) {
      const int kc = kt2 * 2 + 2;
      A0c = *(const u16x8*)(wa0 + kc * 512);
      A1c = *(const u16x8*)(wa1 + kc * 512);
      B0c = *(const u16x8*)(bs0 + kc * 512);
      B1c = *(const u16x8*)(bs1 + kc * 512);
    }
    MFMA4(A0n, A1n, B0n, B1n);
  }
#undef MFMA4

  __syncthreads();  // shw/svv visible; sQ safe
  epilogue<false>(sm, a00, a01, a10, a11, seqF + chbase, nullptr, mask, wbuf,
                  esum, part, (long)b * N + ch * 128, b * NCH2 + ch,
                  (long)ch * B + b, t, lane, w, l31, koct, pg, ng);
}

// ---------------------------------------------------------------------------
// finalize: S-reduce (NCH2 partials), vec normalize, GRU (j-split over q),
// w-normalize + out write. grid (4, B).
// ---------------------------------------------------------------------------
__global__ __launch_bounds__(256) void finalize_gru(
    const float* __restrict__ part, const float* __restrict__ esumP, int ecnt,
    const float* __restrict__ hprev, const float* __restrict__ WT,
    const float* __restrict__ UT, const float* __restrict__ bih,
    const float* __restrict__ bhh, const float* __restrict__ wbuf,
    float* __restrict__ out, float* __restrict__ hnew, int N, int T, int step,
    int NP, int B) {
  const int q = blockIdx.x, b = blockIdx.y, t = threadIdx.x;
  __shared__ float sv[256], sh[256], sP[6][4][64];
  float S = 0.f;
  for (int i = 0; i < ecnt; ++i) S += esumP[b * ecnt + i];
  const float inv = __builtin_amdgcn_rcpf(S);
  float a = 0.f;
  for (int cc = 0; cc < NP; ++cc) a += part[((long)cc * B + b) * 256 + t];
  sv[t] = a * inv;
  sh[t] = hprev[b * 256 + t];
  __syncthreads();
  const int j4 = t & 63, dg = t >> 6;
  const int j = q * 64 + j4;
  float g0 = 0, g1 = 0, g2 = 0, g3 = 0, g4 = 0, g5 = 0;
#pragma unroll 4
  for (int d = dg * 64; d < dg * 64 + 64; ++d) {
    const float vd = sv[d], hd = sh[d];
    const float* wr_ = WT + (long)d * 768 + j;
    const float* ur_ = UT + (long)d * 768 + j;
    g0 = fmaf(vd, wr_[0], g0);
    g1 = fmaf(vd, wr_[256], g1);
    g2 = fmaf(vd, wr_[512], g2);
    g3 = fmaf(hd, ur_[0], g3);
    g4 = fmaf(hd, ur_[256], g4);
    g5 = fmaf(hd, ur_[512], g5);
  }
  sP[0][dg][j4] = g0;
  sP[1][dg][j4] = g1;
  sP[2][dg][j4] = g2;
  sP[3][dg][j4] = g3;
  sP[4][dg][j4] = g4;
  sP[5][dg][j4] = g5;
  __syncthreads();
  if (t < 64) {
    const int jj = q * 64 + t;
    float xr = bih[jj], xz = bih[256 + jj], xn = bih[512 + jj];
    float hr = bhh[jj], hz = bhh[256 + jj], hn = bhh[512 + jj];
#pragma unroll
    for (int dgg = 0; dgg < 4; ++dgg) {
      xr += sP[0][dgg][t];
      xz += sP[1][dgg][t];
      xn += sP[2][dgg][t];
      hr += sP[3][dgg][t];
      hz += sP[4][dgg][t];
      hn += sP[5][dgg][t];
    }
    float rr = sigmoidf_(xr + hr);
    float zz = sigmoidf_(xz + hz);
    float nn = fast_tanh(xn + rr * hn);
    hnew[b * 256 + jj] = (1.f - zz) * nn + zz * sh[jj];
  }
  const long ob = ((long)b * T + step) * N;
  const int nq = N >> 2;
  for (int i = 0; i * 256 < nq; ++i) {
    const int n = q * nq + i * 256 + t;
    out[ob + n] = wbuf[(long)b * N + n] * inv;
  }
}

// ---------------------------------------------------------------------------
extern "C" void kernel_launch(void* const* d_in, const int* in_sizes, int n_in,
                              void* d_out, int out_size, void* d_ws,
                              size_t ws_size, hipStream_t stream) {
  (void)n_in;
  (void)ws_size;
  const float* seq = (const float*)d_in[0];
  const float* hidden = (const float*)d_in[1];
  const float* mask = (const float*)d_in[2];
  const float* Wseq = (const float*)d_in[4];
  const float* Wh = (const float*)d_in[5];
  const float* vatt = (const float*)d_in[6];
  const float* Wih = (const float*)d_in[7];
  const float* Whh = (const float*)d_in[8];
  const float* bih = (const float*)d_in[9];
  const float* bhh = (const float*)d_in[10];
  float* out = (float*)d_out;

  const int P = in_sizes[6];
  const int H = in_sizes[5] / P;
  const int B = in_sizes[1] / H;
  const int N = in_sizes[2] / B;
  const int T = out_size / (B * N);
  const long M = (long)B * N;
  const int NCH2 = N / 128;

  char* p = (char*)d_ws;
  auto alloc = [&](size_t bytes) {
    char* r = p;
    p += (bytes + 255) & ~(size_t)255;
    return r;
  };
  u16* seqF = (u16*)alloc((size_t)M * 256 * 2);
  u16* WfG = (u16*)alloc((size_t)256 * 256 * 2);
  float* WT = (float*)alloc((size_t)256 * 768 * 4);
  float* UT = (float*)alloc((size_t)256 * 768 * 4);
  float* wbuf = (float*)alloc((size_t)B * N * 4);
  float* hwbuf = (float*)alloc((size_t)B * 256 * 4);
  float* hA = (float*)alloc((size_t)B * 256 * 4);
  float* hB = (float*)alloc((size_t)B * 256 * 4);
  float* part = (float*)alloc((size_t)NCH2 * B * 256 * 4);
  float* esum = (float*)alloc((size_t)B * NCH2 * 4);
  float* hbuf[2] = {hA, hB};

  prep_w<<<dim3(56), dim3(256), 0, stream>>>(Wseq, Wih, Whh, WfG, WT, UT);

  for (int t = 0; t < T; ++t) {
    const float* hcur = (t == 0) ? hidden : hbuf[(t - 1) & 1];
    hw_q<<<dim3(4, B), dim3(256), 0, stream>>>(hcur, Wh, hwbuf);
    if (t == 0) {
      step0k<<<dim3(NCH2 / 2, B), dim3(512), 0, stream>>>(
          seq, seqF, WfG, hwbuf, vatt, mask, wbuf, esum, part, N, NCH2, B);
    } else {
      step1k<<<dim3(NCH2, B), dim3(512), 0, stream>>>(
          seqF, WfG, hwbuf, vatt, mask, wbuf, esum, part, N, NCH2, B);
    }
    finalize_gru<<<dim3(4, B), dim3(256), 0, stream>>>(
        part, esum, NCH2, hcur, WT, UT, bih, bhh, wbuf, out, hbuf[t & 1], N, T,
        t, NCH2, B);
  }
}

// Round 17
// 140.866 us; speedup vs baseline: 1.1876x; 1.1876x over previous
//
#include <hip/hip_runtime.h>
#include <cstdint>

using u16 = unsigned short;
using u32 = unsigned int;
typedef __attribute__((ext_vector_type(8))) short bf16x8;
typedef __attribute__((ext_vector_type(8))) u16 u16x8;
typedef __attribute__((ext_vector_type(16))) float f32x16;
typedef __attribute__((ext_vector_type(2))) u32 u32x2;
typedef __attribute__((ext_vector_type(4))) u32 u32x4;

#define DEV static __device__ __forceinline__

DEV u16 bf16_rne(float x) {
  u32 u = __float_as_uint(x);
  u32 r = (u + 0x7FFFu + ((u >> 16) & 1u)) >> 16;
  return (u16)r;
}
DEV float bf16f(u16 h) { return __uint_as_float(((u32)h) << 16); }

DEV u32 cvt_pk_bf16(float lo, float hi) {
  u32 d;
  asm("v_cvt_pk_bf16_f32 %0, %1, %2" : "=v"(d) : "v"(lo), "v"(hi));
  return d;
}

// tanh/sigmoid via v_rcp_f32 (1 ulp) instead of IEEE divide (~10-op chain).
DEV float fast_tanh(float x) {
  float e = __expf(2.0f * x);
  return fmaf(-2.0f, __builtin_amdgcn_rcpf(e + 1.0f), 1.0f);
}
DEV float sigmoidf_(float x) {
  return __builtin_amdgcn_rcpf(1.0f + __expf(-x));
}

// ---------------------------------------------------------------------------
// prep_all: bid<32: WfG = W_seq^T in A-fragment order (unit (pt8*16+kt)*512
// elems: p = pt8*32+(lane&31), d = kt*16+(lane>>5)*8+e).
// bid in [32,56): GRU weight transposes (lanes = g, coalesced stores).
// bid >= 56: hw(h0) = h0 @ W_h  (fused t=0 hw_q; 256 blocks).
// ---------------------------------------------------------------------------
__global__ __launch_bounds__(256) void prep_all(
    const float* __restrict__ Wseq, const float* __restrict__ Wih,
    const float* __restrict__ Whh, u16* __restrict__ WfG,
    float* __restrict__ WT, float* __restrict__ UT,
    const float* __restrict__ h0, const float* __restrict__ Wh,
    float* __restrict__ hw) {
  const int bid = blockIdx.x, t = threadIdx.x;
  if (bid < 32) {
    const int unit = bid * 4 + (t >> 6);
    const int lane = t & 63, l31 = lane & 31, koct = lane >> 5;
    const int pt8 = unit >> 4, kt = unit & 15;
    u16x8 o;
#pragma unroll
    for (int e = 0; e < 8; ++e)
      o[e] = bf16_rne(
          Wseq[(long)(kt * 16 + koct * 8 + e) * 256 + pt8 * 32 + l31]);
    *(u16x8*)(WfG + (long)unit * 512 + lane * 8) = o;
  } else if (bid < 56) {
    const int gid = bid - 32;  // 0..23
    const float* src = (gid >= 12) ? Whh : Wih;
    float* dst = (gid >= 12) ? UT : WT;
    const int g = (gid % 12) * 64 + (t & 63);
    const int dq = t >> 6;
#pragma unroll 4
    for (int d = dq * 64; d < dq * 64 + 64; ++d)
      dst[(long)d * 768 + g] = src[(long)g * 256 + d];
  } else {
    const int idx = bid - 56;  // 0..255
    const int q = idx & 3, b = idx >> 2;
    __shared__ float sh[256];
    __shared__ float sP[4][64];
    sh[t] = h0[b * 256 + t];
    __syncthreads();
    const int j4 = t & 63, dg = t >> 6;
    const int j = q * 64 + j4;
    float g = 0.f;
#pragma unroll 4
    for (int k = dg * 64; k < dg * 64 + 64; ++k)
      g = fmaf(sh[k], Wh[(long)k * 256 + j], g);
    sP[dg][j4] = g;
    __syncthreads();
    if (t < 64)
      hw[b * 256 + q * 64 + t] = (sP[0][t] + sP[1][t]) + (sP[2][t] + sP[3][t]);
  }
}

// ---------------------------------------------------------------------------
// hw_q: hw[b][q*64..] = (h[b] @ W_h)[q*64..]; grid (4,B). (steps >= 1)
// ---------------------------------------------------------------------------
__global__ __launch_bounds__(256) void hw_q(const float* __restrict__ h,
                                            const float* __restrict__ Wh,
                                            float* __restrict__ hw) {
  const int q = blockIdx.x, b = blockIdx.y, t = threadIdx.x;
  __shared__ float sh[256];
  __shared__ float sP[4][64];
  sh[t] = h[b * 256 + t];
  __syncthreads();
  const int j4 = t & 63, dg = t >> 6;
  const int j = q * 64 + j4;
  float g = 0.f;
#pragma unroll 4
  for (int k = dg * 64; k < dg * 64 + 64; ++k)
    g = fmaf(sh[k], Wh[(long)k * 256 + j], g);
  sP[dg][j4] = g;
  __syncthreads();
  if (t < 64)
    hw[b * 256 + q * 64 + t] = (sP[0][t] + sP[1][t]) + (sP[2][t] + sP[3][t]);
}

// ---------------------------------------------------------------------------
// Shared epilogue (128-row chunks): scores via 4-way-split accumulators,
// max-free exp, chunk esum, vec partials (LDS tile or global seqF frags).
// ---------------------------------------------------------------------------
struct EpiSmem {
  float sQ[128][5];
  float se[128];
  float shw[256];
  float svv[256];
  float sredE[2];
};

template <bool FROMLDS>
DEV void epilogue(EpiSmem& sm, const f32x16& a00, const f32x16& a01,
                  const f32x16& a10, const f32x16& a11, const u16* bs,
                  const char* sRb, const float* __restrict__ mask,
                  float* __restrict__ wbuf, float* __restrict__ esum,
                  float* __restrict__ part, long nbase, int esumIdx,
                  long partBase, int t, int lane, int w, int l31, int koct,
                  int pg, int ng) {
  float s0a = 0.f, s0b = 0.f, s0c = 0.f, s0d = 0.f;
  float s1a = 0.f, s1b = 0.f, s1c = 0.f, s1d = 0.f;
#pragma unroll
  for (int r = 0; r < 16; r += 4) {
    const int c0 = (r & 3) + 8 * (r >> 2) + 4 * koct;
    const int c1 = ((r + 1) & 3) + 8 * ((r + 1) >> 2) + 4 * koct;
    const int c2 = ((r + 2) & 3) + 8 * ((r + 2) >> 2) + 4 * koct;
    const int c3 = ((r + 3) & 3) + 8 * ((r + 3) >> 2) + 4 * koct;
    const int p0 = pg * 64 + c0, p1 = pg * 64 + c1, p2 = pg * 64 + c2,
              p3 = pg * 64 + c3;
    s0a = fmaf(sm.svv[p0], fast_tanh(a00[r] + sm.shw[p0]), s0a);
    s0b = fmaf(sm.svv[p1], fast_tanh(a00[r + 1] + sm.shw[p1]), s0b);
    s0c = fmaf(sm.svv[p2], fast_tanh(a00[r + 2] + sm.shw[p2]), s0c);
    s0d = fmaf(sm.svv[p3], fast_tanh(a00[r + 3] + sm.shw[p3]), s0d);
    s1a = fmaf(sm.svv[p0], fast_tanh(a01[r] + sm.shw[p0]), s1a);
    s1b = fmaf(sm.svv[p1], fast_tanh(a01[r + 1] + sm.shw[p1]), s1b);
    s1c = fmaf(sm.svv[p2], fast_tanh(a01[r + 2] + sm.shw[p2]), s1c);
    s1d = fmaf(sm.svv[p3], fast_tanh(a01[r + 3] + sm.shw[p3]), s1d);
  }
#pragma unroll
  for (int r = 0; r < 16; r += 4) {
    const int c0 = (r & 3) + 8 * (r >> 2) + 4 * koct;
    const int c1 = ((r + 1) & 3) + 8 * ((r + 1) >> 2) + 4 * koct;
    const int c2 = ((r + 2) & 3) + 8 * ((r + 2) >> 2) + 4 * koct;
    const int c3 = ((r + 3) & 3) + 8 * ((r + 3) >> 2) + 4 * koct;
    const int p0 = pg * 64 + 32 + c0, p1 = pg * 64 + 32 + c1,
              p2 = pg * 64 + 32 + c2, p3 = pg * 64 + 32 + c3;
    s0a = fmaf(sm.svv[p0], fast_tanh(a10[r] + sm.shw[p0]), s0a);
    s0b = fmaf(sm.svv[p1], fast_tanh(a10[r + 1] + sm.shw[p1]), s0b);
    s0c = fmaf(sm.svv[p2], fast_tanh(a10[r + 2] + sm.shw[p2]), s0c);
    s0d = fmaf(sm.svv[p3], fast_tanh(a10[r + 3] + sm.shw[p3]), s0d);
    s1a = fmaf(sm.svv[p0], fast_tanh(a11[r] + sm.shw[p0]), s1a);
    s1b = fmaf(sm.svv[p1], fast_tanh(a11[r + 1] + sm.shw[p1]), s1b);
    s1c = fmaf(sm.svv[p2], fast_tanh(a11[r + 2] + sm.shw[p2]), s1c);
    s1d = fmaf(sm.svv[p3], fast_tanh(a11[r + 3] + sm.shw[p3]), s1d);
  }
  float sc0 = (s0a + s0b) + (s0c + s0d);
  float sc1 = (s1a + s1b) + (s1c + s1d);
  sc0 += __shfl_xor(sc0, 32, 64);
  sc1 += __shfl_xor(sc1, 32, 64);
  if (koct == 0) {
    sm.sQ[ng * 64 + l31][pg] = sc0;
    sm.sQ[ng * 64 + 32 + l31][pg] = sc1;
  }
  __syncthreads();
  if (t < 128) {
    float s = (sm.sQ[t][0] + sm.sQ[t][1]) + (sm.sQ[t][2] + sm.sQ[t][3]);
    const long n = nbase + t;
    float e = (mask[n] > 0.f) ? __expf(s) : 0.f;
    sm.se[t] = e;
    wbuf[n] = e;
    float s4 = e;
#pragma unroll
    for (int off = 1; off < 64; off <<= 1) s4 += __shfl_xor(s4, off, 64);
    if ((t & 63) == 0) sm.sredE[t >> 6] = s4;
  }
  __syncthreads();
  if (t == 0) esum[esumIdx] = sm.sredE[0] + sm.sredE[1];

  // vec partials: wave w covers kt = w and w+8
#pragma unroll
  for (int kk = 0; kk < 2; ++kk) {
    const int kt = w + kk * 8;
    float vd0 = 0, vd1 = 0, vd2 = 0, vd3 = 0, vd4 = 0, vd5 = 0, vd6 = 0,
          vd7 = 0;
#pragma unroll
    for (int t8 = 0; t8 < 4; ++t8) {
      u16x8 q;
      if constexpr (FROMLDS) {
        const int row = t8 * 32 + l31;
        const int colb = (kt * 16 + koct * 8) * 2;
        q = *(const u16x8*)(sRb + row * 512 + (colb ^ ((row & 31) << 4)));
      } else {
        q = *(const u16x8*)(bs + ((long)(t8 * 16 + kt) * 64 + lane) * 8);
      }
      const float wv = sm.se[t8 * 32 + l31];
      vd0 = fmaf(wv, bf16f((u16)q[0]), vd0);
      vd1 = fmaf(wv, bf16f((u16)q[1]), vd1);
      vd2 = fmaf(wv, bf16f((u16)q[2]), vd2);
      vd3 = fmaf(wv, bf16f((u16)q[3]), vd3);
      vd4 = fmaf(wv, bf16f((u16)q[4]), vd4);
      vd5 = fmaf(wv, bf16f((u16)q[5]), vd5);
      vd6 = fmaf(wv, bf16f((u16)q[6]), vd6);
      vd7 = fmaf(wv, bf16f((u16)q[7]), vd7);
    }
#pragma unroll
    for (int off = 1; off < 32; off <<= 1) {
      vd0 += __shfl_xor(vd0, off, 64);
      vd1 += __shfl_xor(vd1, off, 64);
      vd2 += __shfl_xor(vd2, off, 64);
      vd3 += __shfl_xor(vd3, off, 64);
      vd4 += __shfl_xor(vd4, off, 64);
      vd5 += __shfl_xor(vd5, off, 64);
      vd6 += __shfl_xor(vd6, off, 64);
      vd7 += __shfl_xor(vd7, off, 64);
    }
    if (l31 == 0) {
      float4 o0 = {vd0, vd1, vd2, vd3};
      float4 o1 = {vd4, vd5, vd6, vd7};
      float* pp = part + partBase * 256 + kt * 16 + koct * 8;
      *(float4*)pp = o0;
      *(float4*)(pp + 4) = o1;
    }
  }
}

// ---------------------------------------------------------------------------
// step0k: 128-row chunk; dense per-wave-row f32 reads -> cvt -> swizzled LDS
// -> GEMM (first: matrix pipe starts immediately) -> seqF writeout (stores
// drain under epilogue) -> epilogue (vec partials from the LDS tile).
// ---------------------------------------------------------------------------
__global__ __launch_bounds__(512, 4) void step0k(
    const float* __restrict__ seq, u16* __restrict__ seqF,
    const u16* __restrict__ WfG, const float* __restrict__ hwbuf,
    const float* __restrict__ vatt, const float* __restrict__ mask,
    float* __restrict__ wbuf, float* __restrict__ esum,
    float* __restrict__ part, int N, int NCH2, int B) {
  __shared__ __align__(16) u16 sR[32768];  // 64 KB tile
  __shared__ EpiSmem sm;

  const int t = threadIdx.x, lane = t & 63, w = t >> 6;
  const int l31 = lane & 31, koct = lane >> 5;
  const int pg = w >> 1, ng = w & 1;
  const int b = blockIdx.y, ch = blockIdx.x;
  char* sRb = (char*)sR;
  const long chbase = (long)(b * NCH2 + ch) << 15;

  const u16* wa0 = WfG + (long)(pg * 32) * 512 + lane * 8;
  const u16* wa1 = wa0 + 8192;

  {  // fill: each wave reads one full 1 KB row per iteration (dense)
    const float* src = seq + ((long)b * N + ch * 128) * 256;
#pragma unroll
    for (int i = 0; i < 16; ++i) {
      const int idx = i * 2048 + t * 4;  // floats; row uniform per wave
      float4 x = *(const float4*)(src + idx);
      u32x2 o;
      o[0] = cvt_pk_bf16(x.x, x.y);
      o[1] = cvt_pk_bf16(x.z, x.w);
      const int row = idx >> 8, colb = (idx & 255) * 2;
      *(u32x2*)(sRb + row * 512 + (colb ^ ((row & 31) << 4))) = o;
    }
  }
  if (t < 256) {
    sm.shw[t] = hwbuf[b * 256 + t];
    sm.svv[t] = vatt[t];
  }
  __syncthreads();

  // GEMM first: MFMA issue starts right after the barrier.
  f32x16 a00 = (f32x16)0.f, a01 = (f32x16)0.f, a10 = (f32x16)0.f,
         a11 = (f32x16)0.f;
  {
    const int row0 = ng * 64 + l31, row1 = row0 + 32;
    const char* p0 = sRb + row0 * 512;
    const char* p1 = sRb + row1 * 512;
    const int sw0 = (row0 & 31) << 4, sw1 = (row1 & 31) << 4;
    const int cb = koct * 16;
#pragma unroll 4
    for (int kt = 0; kt < 16; ++kt) {
      bf16x8 af0 = *(const bf16x8*)(wa0 + kt * 512);
      bf16x8 af1 = *(const bf16x8*)(wa1 + kt * 512);
      bf16x8 bf0 = *(const bf16x8*)(p0 + ((kt * 32 + cb) ^ sw0));
      bf16x8 bf1 = *(const bf16x8*)(p1 + ((kt * 32 + cb) ^ sw1));
      a00 = __builtin_amdgcn_mfma_f32_32x32x16_bf16(af0, bf0, a00, 0, 0, 0);
      a01 = __builtin_amdgcn_mfma_f32_32x32x16_bf16(af0, bf1, a01, 0, 0, 0);
      a10 = __builtin_amdgcn_mfma_f32_32x32x16_bf16(af1, bf0, a10, 0, 0, 0);
      a11 = __builtin_amdgcn_mfma_f32_32x32x16_bf16(af1, bf1, a11, 0, 0, 0);
    }
  }

  {  // writeout fragment-order seqF (stores drain under the epilogue)
    u16* dst = seqF + chbase;
#pragma unroll
    for (int i = 0; i < 8; ++i) {
      const int uidx = i * 512 + t;
      const int ln = uidx & 63, unit = uidx >> 6;
      const int kt = unit & 15, t8 = unit >> 4;
      const int row = t8 * 32 + (ln & 31);
      const int colb = (kt * 16 + (ln >> 5) * 8) * 2;
      u16x8 v = *(const u16x8*)(sRb + row * 512 + (colb ^ ((row & 31) << 4)));
      *(u16x8*)(dst + (long)uidx * 8) = v;
    }
  }
  __syncthreads();  // sR reads done; sQ reuse safe (sR kept for vec partial)
  epilogue<true>(sm, a00, a01, a10, a11, nullptr, sRb, mask, wbuf, esum, part,
                 (long)b * N + ch * 128, b * NCH2 + ch, (long)ch * B + b, t,
                 lane, w, l31, koct, pg, ng);
}

// ---------------------------------------------------------------------------
// step1k: barrier-free streaming GEMM. B-frags ring-prefetched from global
// seqF (MFMA order, 64x16B contiguous); W-frags streamed from L2.
// ---------------------------------------------------------------------------
__global__ __launch_bounds__(512, 4) void step1k(
    const u16* __restrict__ seqF, const u16* __restrict__ WfG,
    const float* __restrict__ hwbuf, const float* __restrict__ vatt,
    const float* __restrict__ mask, float* __restrict__ wbuf,
    float* __restrict__ esum, float* __restrict__ part, int N, int NCH2,
    int B) {
  __shared__ EpiSmem sm;
  const int t = threadIdx.x, lane = t & 63, w = t >> 6;
  const int l31 = lane & 31, koct = lane >> 5;
  const int pg = w >> 1, ng = w & 1;
  const int b = blockIdx.y, ch = blockIdx.x;
  const long chbase = (long)(b * NCH2 + ch) << 15;

  if (t < 256) {
    sm.shw[t] = hwbuf[b * 256 + t];
    sm.svv[t] = vatt[t];
  }

  const u16* bs0 = seqF + chbase + ng * 16384 + lane * 8;
  const u16* bs1 = bs0 + 8192;
  const u16* wa0 = WfG + (long)(pg * 32) * 512 + lane * 8;
  const u16* wa1 = wa0 + 8192;

  f32x16 a00 = (f32x16)0.f, a01 = (f32x16)0.f, a10 = (f32x16)0.f,
         a11 = (f32x16)0.f;

  u16x8 A0c, A1c, B0c, B1c, A0n, A1n, B0n, B1n;
  A0c = *(const u16x8*)(wa0);
  A1c = *(const u16x8*)(wa1);
  B0c = *(const u16x8*)(bs0);
  B1c = *(const u16x8*)(bs1);

#define MFMA4(A0, A1, B0, B1)                                                  \
  {                                                                            \
    bf16x8 af0 = *(bf16x8*)&A0, af1 = *(bf16x8*)&A1;                           \
    bf16x8 bf0 = *(bf16x8*)&B0, bf1 = *(bf16x8*)&B1;                           \
    a00 = __builtin_amdgcn_mfma_f32_32x32x16_bf16(af0, bf0, a00, 0, 0, 0);     \
    a01 = __builtin_amdgcn_mfma_f32_32x32x16_bf16(af0, bf1, a01, 0, 0, 0);     \
    a10 = __builtin_amdgcn_mfma_f32_32x32x16_bf16(af1, bf0, a10, 0, 0, 0);     \
    a11 = __builtin_amdgcn_mfma_f32_32x32x16_bf16(af1, bf1, a11, 0, 0, 0);     \
  }

#pragma unroll
  for (int kt2 = 0; kt2 < 8; ++kt2) {
    const int kn = kt2 * 2 + 1;
    A0n = *(const u16x8*)(wa0 + kn * 512);
    A1n = *(const u16x8*)(wa1 + kn * 512);
    B0n = *(const u16x8*)(bs0 + kn * 512);
    B1n = *(const u16x8*)(bs1 + kn * 512);
    MFMA4(A0c, A1c, B0c, B1c);
    if (kt2 < 7) {
      const int kc = kt2 * 2 + 2;
      A0c = *(const u16x8*)(wa0 + kc * 512);
      A1c = *(const u16x8*)(wa1 + kc * 512);
      B0c = *(const u16x8*)(bs0 + kc * 512);
      B1c = *(const u16x8*)(bs1 + kc * 512);
    }
    MFMA4(A0n, A1n, B0n, B1n);
  }
#undef MFMA4

  __syncthreads();  // shw/svv visible; sQ safe
  epilogue<false>(sm, a00, a01, a10, a11, seqF + chbase, nullptr, mask, wbuf,
                  esum, part, (long)b * N + ch * 128, b * NCH2 + ch,
                  (long)ch * B + b, t, lane, w, l31, koct, pg, ng);
}

// ---------------------------------------------------------------------------
// finalize: S-reduce (NCH2 partials), vec normalize, GRU (j-split over q),
// w-normalize + out write. grid (4, B).
// ---------------------------------------------------------------------------
__global__ __launch_bounds__(256) void finalize_gru(
    const float* __restrict__ part, const float* __restrict__ esumP, int ecnt,
    const float* __restrict__ hprev, const float* __restrict__ WT,
    const float* __restrict__ UT, const float* __restrict__ bih,
    const float* __restrict__ bhh, const float* __restrict__ wbuf,
    float* __restrict__ out, float* __restrict__ hnew, int N, int T, int step,
    int NP, int B) {
  const int q = blockIdx.x, b = blockIdx.y, t = threadIdx.x;
  __shared__ float sv[256], sh[256], sP[6][4][64];
  float S = 0.f;
  for (int i = 0; i < ecnt; ++i) S += esumP[b * ecnt + i];
  const float inv = __builtin_amdgcn_rcpf(S);
  float a = 0.f;
  for (int cc = 0; cc < NP; ++cc) a += part[((long)cc * B + b) * 256 + t];
  sv[t] = a * inv;
  sh[t] = hprev[b * 256 + t];
  __syncthreads();
  const int j4 = t & 63, dg = t >> 6;
  const int j = q * 64 + j4;
  float g0 = 0, g1 = 0, g2 = 0, g3 = 0, g4 = 0, g5 = 0;
#pragma unroll 4
  for (int d = dg * 64; d < dg * 64 + 64; ++d) {
    const float vd = sv[d], hd = sh[d];
    const float* wr_ = WT + (long)d * 768 + j;
    const float* ur_ = UT + (long)d * 768 + j;
    g0 = fmaf(vd, wr_[0], g0);
    g1 = fmaf(vd, wr_[256], g1);
    g2 = fmaf(vd, wr_[512], g2);
    g3 = fmaf(hd, ur_[0], g3);
    g4 = fmaf(hd, ur_[256], g4);
    g5 = fmaf(hd, ur_[512], g5);
  }
  sP[0][dg][j4] = g0;
  sP[1][dg][j4] = g1;
  sP[2][dg][j4] = g2;
  sP[3][dg][j4] = g3;
  sP[4][dg][j4] = g4;
  sP[5][dg][j4] = g5;
  __syncthreads();
  if (t < 64) {
    const int jj = q * 64 + t;
    float xr = bih[jj], xz = bih[256 + jj], xn = bih[512 + jj];
    float hr = bhh[jj], hz = bhh[256 + jj], hn = bhh[512 + jj];
#pragma unroll
    for (int dgg = 0; dgg < 4; ++dgg) {
      xr += sP[0][dgg][t];
      xz += sP[1][dgg][t];
      xn += sP[2][dgg][t];
      hr += sP[3][dgg][t];
      hz += sP[4][dgg][t];
      hn += sP[5][dgg][t];
    }
    float rr = sigmoidf_(xr + hr);
    float zz = sigmoidf_(xz + hz);
    float nn = fast_tanh(xn + rr * hn);
    hnew[b * 256 + jj] = (1.f - zz) * nn + zz * sh[jj];
  }
  const long ob = ((long)b * T + step) * N;
  const int nq = N >> 2;
  for (int i = 0; i * 256 < nq; ++i) {
    const int n = q * nq + i * 256 + t;
    out[ob + n] = wbuf[(long)b * N + n] * inv;
  }
}

// ---------------------------------------------------------------------------
extern "C" void kernel_launch(void* const* d_in, const int* in_sizes, int n_in,
                              void* d_out, int out_size, void* d_ws,
                              size_t ws_size, hipStream_t stream) {
  (void)n_in;
  (void)ws_size;
  const float* seq = (const float*)d_in[0];
  const float* hidden = (const float*)d_in[1];
  const float* mask = (const float*)d_in[2];
  const float* Wseq = (const float*)d_in[4];
  const float* Wh = (const float*)d_in[5];
  const float* vatt = (const float*)d_in[6];
  const float* Wih = (const float*)d_in[7];
  const float* Whh = (const float*)d_in[8];
  const float* bih = (const float*)d_in[9];
  const float* bhh = (const float*)d_in[10];
  float* out = (float*)d_out;

  const int P = in_sizes[6];
  const int H = in_sizes[5] / P;
  const int B = in_sizes[1] / H;
  const int N = in_sizes[2] / B;
  const int T = out_size / (B * N);
  const long M = (long)B * N;
  const int NCH2 = N / 128;

  char* p = (char*)d_ws;
  auto alloc = [&](size_t bytes) {
    char* r = p;
    p += (bytes + 255) & ~(size_t)255;
    return r;
  };
  u16* seqF = (u16*)alloc((size_t)M * 256 * 2);
  u16* WfG = (u16*)alloc((size_t)256 * 256 * 2);
  float* WT = (float*)alloc((size_t)256 * 768 * 4);
  float* UT = (float*)alloc((size_t)256 * 768 * 4);
  float* wbuf = (float*)alloc((size_t)B * N * 4);
  float* hwbuf = (float*)alloc((size_t)B * 256 * 4);
  float* hA = (float*)alloc((size_t)B * 256 * 4);
  float* hB = (float*)alloc((size_t)B * 256 * 4);
  float* part = (float*)alloc((size_t)NCH2 * B * 256 * 4);
  float* esum = (float*)alloc((size_t)B * NCH2 * 4);
  float* hbuf[2] = {hA, hB};

  prep_all<<<dim3(56 + 4 * B), dim3(256), 0, stream>>>(
      Wseq, Wih, Whh, WfG, WT, UT, hidden, Wh, hwbuf);

  for (int t = 0; t < T; ++t) {
    const float* hcur = (t == 0) ? hidden : hbuf[(t - 1) & 1];
    if (t > 0) {
      hw_q<<<dim3(4, B), dim3(256), 0, stream>>>(hcur, Wh, hwbuf);
    }
    if (t == 0) {
      step0k<<<dim3(NCH2, B), dim3(512), 0, stream>>>(
          seq, seqF, WfG, hwbuf, vatt, mask, wbuf, esum, part, N, NCH2, B);
    } else {
      step1k<<<dim3(NCH2, B), dim3(512), 0, stream>>>(
          seqF, WfG, hwbuf, vatt, mask, wbuf, esum, part, N, NCH2, B);
    }
    finalize_gru<<<dim3(4, B), dim3(256), 0, stream>>>(
        part, esum, NCH2, hcur, WT, UT, bih, bhh, wbuf, out, hbuf[t & 1], N, T,
        t, NCH2, B);
  }
}